// Round 8
// baseline (33.816 us; speedup 1.0000x reference)
//
#include <hip/hip_runtime.h>
#include <cmath>

// RTMDet decode, fused: float4 cls loads + 2-way class split + LDS merge + FORCED 8-deep
// load pipeline (asm liveness pins -- R7's compiler-defeated prefetch, done properly).
// Per spatial position: conf = sigmoid(max_c logit), class = argmax_c logit (first occurrence),
// box = clip([gx-l, gy-t, gx+r, gy+d], 0, 639), gx = w*step, gy = h*step.
// Output layout (flat float32 in d_out): boxes [64,8400,4] | scores [64,8400] | classes [64,8400].
//
// R7 post-mortem: VGPR_Count stayed 32 -> the compiler collapsed the software pipeline
// (8 x float4 double-buffer cannot fit in 32 VGPRs). Here each issue group of 8 loads is
// followed by asm volatile("" : "+v"(reg)) pins, forcing all 8 results live -> regalloc must
// keep the pipeline. Two alternating batches (A/B), 5 static stages, all indices compile-time.
//
// Grid: 1050 blocks x 256 threads, level boundaries on block boundaries:
//   [0,800) -> level 0 (80x80, s8) | [800,1000) -> level 1 (40x40, s16) | [1000,1050) -> lvl 2.

constexpr int B_   = 64;
constexpr int NC   = 80;
constexpr int NTOT = 8400;   // 6400 + 1600 + 400

typedef float f32x4 __attribute__((ext_vector_type(4)));

__device__ __forceinline__ float sigmoidf_(float x) { return 1.0f / (1.0f + __expf(-x)); }

template<int HW, int W, int STEP, int NOFF>
__device__ __forceinline__ void decode_level(
    const float* __restrict__ cls, const float* __restrict__ box,
    float* __restrict__ oboxes, float* __restrict__ oscores, float* __restrict__ oclasses,
    int lbid, int tid,
    float (* __restrict__ sm)[256], int* __restrict__ spk)
{
    constexpr int QPI = HW / 4;                 // quads per image
    constexpr int PPI = HW / 2;                 // pairs per image

    int half = tid >> 7;                        // class half: 0 -> [0,40), 1 -> [40,80)
    int lp   = tid & 127;                       // local quad in block
    int quad = lbid * 128 + lp;                 // level-local quad, in [0, 64*QPI)
    int b    = quad / QPI;                      // compile-time QPI -> magic mul
    int p    = (quad - b * QPI) << 2;           // first of 4 consecutive positions

    const float* cbase = cls + (size_t)b * NC * HW + (size_t)(half * 40) * HW + p;
    float m[4]  = {-3.4e38f, -3.4e38f, -3.4e38f, -3.4e38f};
    int   ci[4] = {0, 0, 0, 0};

    f32x4 A0,A1,A2,A3,A4,A5,A6,A7;              // batch buffers (named -> static regalloc)
    f32x4 B0,B1,B2,B3,B4,B5,B6,B7;

    // issue 8 loads for class block 'base', pin all results live (compiler cannot collapse)
#define LOADB(R0,R1,R2,R3,R4,R5,R6,R7, base)                                              \
    R0 = *reinterpret_cast<const f32x4*>(cbase + (size_t)((base) + 0) * HW);              \
    R1 = *reinterpret_cast<const f32x4*>(cbase + (size_t)((base) + 1) * HW);              \
    R2 = *reinterpret_cast<const f32x4*>(cbase + (size_t)((base) + 2) * HW);              \
    R3 = *reinterpret_cast<const f32x4*>(cbase + (size_t)((base) + 3) * HW);              \
    R4 = *reinterpret_cast<const f32x4*>(cbase + (size_t)((base) + 4) * HW);              \
    R5 = *reinterpret_cast<const f32x4*>(cbase + (size_t)((base) + 5) * HW);              \
    R6 = *reinterpret_cast<const f32x4*>(cbase + (size_t)((base) + 6) * HW);              \
    R7 = *reinterpret_cast<const f32x4*>(cbase + (size_t)((base) + 7) * HW);              \
    asm volatile("" : "+v"(R0), "+v"(R1), "+v"(R2), "+v"(R3),                             \
                      "+v"(R4), "+v"(R5), "+v"(R6), "+v"(R7));

#define RED1(R, c)                                                                        \
    { _Pragma("unroll")                                                                   \
      for (int j = 0; j < 4; ++j)                                                         \
          if (R[j] > m[j]) { m[j] = R[j]; ci[j] = (c); } }   /* strict > : first occurrence */

#define REDB(R0,R1,R2,R3,R4,R5,R6,R7, base)                                               \
    RED1(R0, (base)+0) RED1(R1, (base)+1) RED1(R2, (base)+2) RED1(R3, (base)+3)           \
    RED1(R4, (base)+4) RED1(R5, (base)+5) RED1(R6, (base)+6) RED1(R7, (base)+7)

    LOADB(A0,A1,A2,A3,A4,A5,A6,A7,  0)          // prologue: batch 0 in flight
    LOADB(B0,B1,B2,B3,B4,B5,B6,B7,  8)          // batch 1 in flight
    REDB (A0,A1,A2,A3,A4,A5,A6,A7,  0)
    LOADB(A0,A1,A2,A3,A4,A5,A6,A7, 16)          // batch 2
    REDB (B0,B1,B2,B3,B4,B5,B6,B7,  8)
    LOADB(B0,B1,B2,B3,B4,B5,B6,B7, 24)          // batch 3
    REDB (A0,A1,A2,A3,A4,A5,A6,A7, 16)
    LOADB(A0,A1,A2,A3,A4,A5,A6,A7, 32)          // batch 4
    REDB (B0,B1,B2,B3,B4,B5,B6,B7, 24)
    REDB (A0,A1,A2,A3,A4,A5,A6,A7, 32)

#undef LOADB
#undef RED1
#undef REDB

    #pragma unroll
    for (int j = 0; j < 4; ++j) sm[j][tid] = m[j];
    spk[tid] = ci[0] | (ci[1] << 8) | (ci[2] << 16) | (ci[3] << 24);
    __syncthreads();

    if (tid < 128) {                            // merge: low half owns the quad
        int pr  = tid + 128;
        int opk = spk[pr];
        float4 osc, ocl;
        float* oscp = &osc.x;
        float* oclp = &ocl.x;
        #pragma unroll
        for (int j = 0; j < 4; ++j) {
            float om = sm[j][pr];
            int   oc = ((opk >> (8 * j)) & 0xFF) + 40;
            float mm = m[j];
            int   cc = ci[j];                   // already global (half 0)
            if (om > mm) { mm = om; cc = oc; }  // ties -> lower index = mine
            oscp[j] = sigmoidf_(mm);
            oclp[j] = (float)cc;
        }
        size_t obase = (size_t)b * NTOT + NOFF + p;
        *reinterpret_cast<float4*>(oscores  + obase) = osc;   // lanes contiguous -> coalesced
        *reinterpret_cast<float4*>(oclasses + obase) = ocl;
    }

    // ---------- boxes: 1 pair (2 consecutive positions) per thread ----------
    {
        int pair = lbid * 256 + tid;            // level-local pair, in [0, 64*PPI)
        int bb   = pair / PPI;                  // compile-time PPI -> magic mul
        int pp   = (pair - bb * PPI) << 1;
        int hh   = pp / W;                      // compile-time W -> magic mul
        int ww   = pp - hh * W;

        const float* bbase = box + (size_t)bb * 4 * HW + pp;
        float2 bl = *reinterpret_cast<const float2*>(bbase);
        float2 bt = *reinterpret_cast<const float2*>(bbase + HW);
        float2 br = *reinterpret_cast<const float2*>(bbase + 2 * HW);
        float2 bd = *reinterpret_cast<const float2*>(bbase + 3 * HW);

        float gy = (float)(hh * STEP);
        size_t ob = (size_t)bb * NTOT + NOFF + pp;
        #pragma unroll
        for (int j = 0; j < 2; ++j) {
            float gx = (float)((ww + j) * STEP);
            float l  = j ? bl.y : bl.x;
            float tt = j ? bt.y : bt.x;
            float r  = j ? br.y : br.x;
            float dd = j ? bd.y : bd.x;
            float4 o;
            o.x = fminf(fmaxf(gx - l,  0.0f), 639.0f);
            o.y = fminf(fmaxf(gy - tt, 0.0f), 639.0f);
            o.z = fminf(fmaxf(gx + r,  0.0f), 639.0f);
            o.w = fminf(fmaxf(gy + dd, 0.0f), 639.0f);
            *reinterpret_cast<float4*>(oboxes + (ob + j) * 4) = o;  // coalesced float4
        }
    }
}

__global__ __launch_bounds__(256, 4) void rtmdet_decode_fused(
    const float* __restrict__ cls0, const float* __restrict__ box0,
    const float* __restrict__ cls1, const float* __restrict__ box1,
    const float* __restrict__ cls2, const float* __restrict__ box2,
    float* __restrict__ oboxes, float* __restrict__ oscores, float* __restrict__ oclasses)
{
    __shared__ float sm[4][256];
    __shared__ int   spk[256];

    int bid = blockIdx.x;
    int tid = threadIdx.x;
    if (bid < 800) {
        decode_level<6400, 80,  8,    0>(cls0, box0, oboxes, oscores, oclasses, bid,
                                         tid, sm, spk);
    } else if (bid < 1000) {
        decode_level<1600, 40, 16, 6400>(cls1, box1, oboxes, oscores, oclasses, bid - 800,
                                         tid, sm, spk);
    } else {
        decode_level< 400, 20, 32, 8000>(cls2, box2, oboxes, oscores, oclasses, bid - 1000,
                                         tid, sm, spk);
    }
}

extern "C" void kernel_launch(void* const* d_in, const int* in_sizes, int n_in,
                              void* d_out, int out_size, void* d_ws, size_t ws_size,
                              hipStream_t stream) {
    const float* cls0 = (const float*)d_in[0];
    const float* box0 = (const float*)d_in[1];
    const float* cls1 = (const float*)d_in[2];
    const float* box1 = (const float*)d_in[3];
    const float* cls2 = (const float*)d_in[4];
    const float* box2 = (const float*)d_in[5];

    float* oboxes   = (float*)d_out;
    float* oscores  = oboxes  + (size_t)B_ * NTOT * 4;
    float* oclasses = oscores + (size_t)B_ * NTOT;

    rtmdet_decode_fused<<<1050, 256, 0, stream>>>(cls0, box0, cls1, box1, cls2, box2,
                                                  oboxes, oscores, oclasses);
}